// Round 6
// baseline (259.917 us; speedup 1.0000x reference)
//
#include <hip/hip_runtime.h>
#include <stdint.h>

// ---------------------------------------------------------------------------
// MultiHeadAttention  B=2 S=2048 D=1024 H=16 HD=64   (fp32 in/out, bf16 MFMA)
// convert->bf16, fused QKV GEMM, flash attention (S^T form, x32 PV, s-split
// partials), output GEMM with FUSED partial-combine (attn_reduce deleted).
// Round change vs r5: 5 kernels -> 4. gemm_bt<1> A-staging now reads the two
// s-half partials OP0/OP1, combines (a+b)*rl in registers (rl from a 4KB
// per-block LDS table of 1/(LS0+LS1), one head per K-iter), and ds_writes
// the bf16 tile -- T14 split: loads issued before compute, combine after.
// attn_reduce kernel + attnb round-trip removed. attn unchanged except
// __launch_bounds__(256,5) (tail rebalance; 5x32KB = 160KB exact).
// ---------------------------------------------------------------------------

typedef __bf16 bf16x8 __attribute__((ext_vector_type(8)));
typedef float  f32x4  __attribute__((ext_vector_type(4)));

#define LOG2E 1.44269504088896f
#define FIXED_MAX_BITS 14.4269504088896f   /* 10 nats * log2(e) */

__device__ __forceinline__ unsigned short f2bf(float f) {
    union { float f; unsigned u; } v; v.f = f;
    unsigned r = v.u + 0x7FFFu + ((v.u >> 16) & 1u);   // round-to-nearest-even
    return (unsigned short)(r >> 16);
}

__device__ __forceinline__ float exp2_fast(float x) {
#if __has_builtin(__builtin_amdgcn_exp2f)
    return __builtin_amdgcn_exp2f(x);
#else
    return __expf(x * 0.69314718056f);
#endif
}

// combine two bf16 pairs (packed in u32) : ((a+b)*rl) -> packed bf16 pair
__device__ __forceinline__ unsigned comb2(unsigned wa, unsigned wb, float rl) {
    union { unsigned u; float f; } la, ha, lb, hb;
    la.u = wa << 16; ha.u = wa & 0xffff0000u;
    lb.u = wb << 16; hb.u = wb & 0xffff0000u;
    float lo = (la.f + lb.f) * rl;
    float hi = (ha.f + hb.f) * rl;
    __bf16 l = (__bf16)lo, h = (__bf16)hi;
    unsigned short lu = __builtin_bit_cast(unsigned short, l);
    unsigned short hu = __builtin_bit_cast(unsigned short, h);
    return (unsigned)lu | ((unsigned)hu << 16);
}

// async global->LDS, 16B per lane; lds dest = wave-uniform base + lane*16
__device__ __forceinline__ void glds16(const void* g, void* l) {
    __builtin_amdgcn_global_load_lds(
        (__attribute__((address_space(1))) void*)(g),
        (__attribute__((address_space(3))) void*)(l),
        16, 0, 0);
}

// ---------------------------------------------------------------------------
// fp32 -> bf16 convert: x (1M float4) + 4 weights (256K float4 each), 1 launch
// ---------------------------------------------------------------------------
__global__ __launch_bounds__(256) void cvt_all(
    const float* __restrict__ x,  const float* __restrict__ Wq,
    const float* __restrict__ Wk, const float* __restrict__ Wv,
    const float* __restrict__ Wo,
    unsigned short* __restrict__ xb,  unsigned short* __restrict__ Wqb,
    unsigned short* __restrict__ Wkb, unsigned short* __restrict__ Wvb,
    unsigned short* __restrict__ Wob)
{
    const int stride = gridDim.x * blockDim.x;
    for (int i = blockIdx.x * blockDim.x + threadIdx.x; i < 2097152; i += stride) {
        const float* src; unsigned short* dst; int j;
        if (i < 1048576) { src = x; dst = xb; j = i; }
        else {
            int t = (i - 1048576) >> 18; j = (i - 1048576) & 262143;
            src = (t == 0) ? Wq : (t == 1) ? Wk : (t == 2) ? Wv : Wo;
            dst = (t == 0) ? Wqb : (t == 1) ? Wkb : (t == 2) ? Wvb : Wob;
        }
        float4 v = ((const float4*)src)[j];
        ushort4 o;
        o.x = f2bf(v.x); o.y = f2bf(v.y); o.z = f2bf(v.z); o.w = f2bf(v.w);
        ((ushort4*)dst)[j] = o;
    }
}

// ---------------------------------------------------------------------------
// GEMM  C[m][n] = sum_k A[m][k] * W[n][k]  (+bias), 2-phase LDS double-buffer
// MODE 0: A = bf16 activations, glds16 staging, 3 projections.
// MODE 1: A = (OP0 + OP1) * rl fused on the fly (attn partial combine);
//         A-staging = reg-load (issue-early) + combine + ds_write (commit
//         after compute). b1 carries LS (partial lsums). W0 = Wo.
// ---------------------------------------------------------------------------
template <int MODE>
__global__ __launch_bounds__(256) void gemm_bt(
    const unsigned short* __restrict__ A,
    const unsigned short* __restrict__ W0,
    const unsigned short* __restrict__ W1,
    const unsigned short* __restrict__ W2,
    const float* __restrict__ b0,
    const float* __restrict__ b1,
    const float* __restrict__ b2,
    unsigned short* __restrict__ outQ,
    unsigned short* __restrict__ outK,
    unsigned short* __restrict__ outV,
    float* __restrict__ outF)
{
    constexpr int BM = (MODE == 0) ? 128 : 64;
    constexpr int FM = BM / 32;
    constexpr int RA = BM / 32;

    __shared__ __attribute__((aligned(16))) unsigned short As[2 * BM * 64];
    __shared__ __attribute__((aligned(16))) unsigned short Bs[2 * 128 * 64];
    __shared__ float Lrec[(MODE == 1) ? 1024 : 4];   // 1/(LS0+LS1) per (row,head)

    const int tid  = threadIdx.x;
    const int lane = tid & 63;
    const int wid  = tid >> 6;
    const int quad = lane >> 4;
    const int l16  = lane & 15;

    const int m0 = blockIdx.x * BM;

    const unsigned short* W;
    const float* bias;
    int proj, n0;
    if (MODE == 0) {
        proj = blockIdx.y >> 3;
        n0   = (blockIdx.y & 7) * 128;
        W    = (proj == 0) ? W0 : (proj == 1) ? W1 : W2;
        bias = (proj == 0) ? b0 : (proj == 1) ? b1 : b2;
    } else {
        proj = 0;
        n0   = blockIdx.y * 128;
        W    = W0;
        bias = b0;
    }

    const int wm = (wid >> 1) * (BM / 2);
    const int wn = (wid & 1) * 64;

    f32x4 acc[FM][4];
#pragma unroll
    for (int i = 0; i < FM; ++i)
#pragma unroll
        for (int j = 0; j < 4; ++j)
            acc[i][j] = (f32x4){0.f, 0.f, 0.f, 0.f};

    char* AsB = (char*)As;
    char* BsB = (char*)Bs;

    // ---- staging helpers -------------------------------------------------
    auto stageB = [&](int k0, int buf) {
        char* ldsB = BsB + buf * 16384 + wid * 1024;
#pragma unroll
        for (int q = 0; q < 4; ++q) {
            int i   = q * 256 + tid;
            int row = i >> 3;
            int sc  = (i & 7) ^ (row & 7);
            glds16(W + (size_t)(n0 + row) * 1024 + k0 + sc * 8, ldsB + q * 4096);
        }
    };
    auto stageA_g = [&](int k0, int buf) {     // MODE 0 path (glds16)
        char* ldsA = AsB + buf * (BM * 128) + wid * 1024;
#pragma unroll
        for (int q = 0; q < RA; ++q) {
            int i   = q * 256 + tid;
            int row = i >> 3;
            int sc  = (i & 7) ^ (row & 7);
            glds16(A + (size_t)(m0 + row) * 1024 + k0 + sc * 8, ldsA + q * 4096);
        }
    };

    // MODE 1: A reg-staging state (2 rounds x 16B from each half)
    uint4 ar0[2], ar1[2];
    float arl[2];
    auto aload = [&](int k0) {
#pragma unroll
        for (int q = 0; q < 2; ++q) {
            int i   = q * 256 + tid;
            int row = i >> 3;
            int sc  = (i & 7) ^ (row & 7);
            const size_t gof = (size_t)(m0 + row) * 1024 + k0 + sc * 8;
            ar0[q] = *(const uint4*)(A + gof);
            ar1[q] = *(const uint4*)(A + 4194304 + gof);
            arl[q] = Lrec[row * 16 + (k0 >> 6)];
        }
    };
    auto acommit = [&](int buf) {
#pragma unroll
        for (int q = 0; q < 2; ++q) {
            int i = q * 256 + tid;
            uint4 o;
            o.x = comb2(ar0[q].x, ar1[q].x, arl[q]);
            o.y = comb2(ar0[q].y, ar1[q].y, arl[q]);
            o.z = comb2(ar0[q].z, ar1[q].z, arl[q]);
            o.w = comb2(ar0[q].w, ar1[q].w, arl[q]);
            *(uint4*)(AsB + buf * (BM * 128) + i * 16) = o;
        }
    };

    // ---- prologue --------------------------------------------------------
    if constexpr (MODE == 1) {
        // per-block reciprocal-lsum table: rows m0..m0+63 x 16 heads
        const float* LSp = b1;
        const int bq16 = (m0 >> 11) << 4;
        const int mq0  = m0 & 2047;
#pragma unroll
        for (int j = 0; j < 4; ++j) {
            int idx = j * 256 + tid;
            int rr  = idx >> 4, h = idx & 15;
            int off = (bq16 + h) * 2048 + mq0 + rr;
            Lrec[idx] = 1.0f / (LSp[off] + LSp[65536 + off]);
        }
        __syncthreads();
        aload(0);
        acommit(0);
        stageB(0, 0);
    } else {
        stageA_g(0, 0);
        stageB(0, 0);
    }
    __syncthreads();

    // ---- main loop -------------------------------------------------------
    for (int k0 = 0; k0 < 1024; k0 += 64) {
        const int cur = (k0 >> 6) & 1;
        const bool pf = (k0 + 64 < 1024);
        if (pf) {
            if constexpr (MODE == 1) {
                aload(k0 + 64);             // issue-early: hides under MFMA
                stageB(k0 + 64, cur ^ 1);
            } else {
                stageA_g(k0 + 64, cur ^ 1);
                stageB(k0 + 64, cur ^ 1);
            }
        }

        const char* AsC = AsB + cur * (BM * 128);
        const char* BsC = BsB + cur * 16384;

#pragma unroll
        for (int kh = 0; kh < 2; ++kh) {
            bf16x8 af[FM], bfr[4];
#pragma unroll
            for (int t = 0; t < FM; ++t) {
                int r = wm + t * 16 + l16;
                int c = (kh * 4 + quad) ^ (r & 7);
                af[t] = *(const bf16x8*)(AsC + r * 128 + c * 16);
            }
#pragma unroll
            for (int t = 0; t < 4; ++t) {
                int r = wn + t * 16 + l16;
                int c = (kh * 4 + quad) ^ (r & 7);
                bfr[t] = *(const bf16x8*)(BsC + r * 128 + c * 16);
            }
#pragma unroll
            for (int i = 0; i < FM; ++i)
#pragma unroll
                for (int j = 0; j < 4; ++j)
                    acc[i][j] = __builtin_amdgcn_mfma_f32_16x16x32_bf16(
                        af[i], bfr[j], acc[i][j], 0, 0, 0);
        }

        if constexpr (MODE == 1) {
            if (pf) acommit(cur ^ 1);       // combine + ds_write after compute
        }
        __syncthreads();   // drains vmcnt/lgkm: prefetch landed, buffers flip
    }

    // ---- epilogue --------------------------------------------------------
#pragma unroll
    for (int i = 0; i < FM; ++i) {
        const int mrow0 = m0 + wm + i * 16 + quad * 4;
#pragma unroll
        for (int j = 0; j < 4; ++j) {
            const int n  = n0 + wn + j * 16 + l16;
            const float bb = bias[n];
            if (MODE == 1) {
#pragma unroll
                for (int r = 0; r < 4; ++r)
                    outF[(size_t)(mrow0 + r) * 1024 + n] = acc[i][j][r] + bb;
            } else {
                const int h = n >> 6, hd = n & 63;
                if (proj == 2) {
                    const int b = mrow0 >> 11, s = mrow0 & 2047;
                    ushort4 pk;
                    pk.x = f2bf(acc[i][j][0] + bb);
                    pk.y = f2bf(acc[i][j][1] + bb);
                    pk.z = f2bf(acc[i][j][2] + bb);
                    pk.w = f2bf(acc[i][j][3] + bb);
                    *(ushort4*)(outV + ((size_t)((b * 16 + h) * 64 + hd)) * 2048 + s) = pk;
                } else {
                    unsigned short* dst = (proj == 0) ? outQ : outK;
                    const float scl = (proj == 0) ? (0.125f * LOG2E) : 1.0f;
#pragma unroll
                    for (int r = 0; r < 4; ++r) {
                        const int m = mrow0 + r;
                        const int b = m >> 11, s = m & 2047;
                        dst[((size_t)((b * 16 + h) * 2048 + s)) * 64 + hd] =
                            f2bf((acc[i][j][r] + bb) * scl);
                    }
                }
            }
        }
    }
}

// ---------------------------------------------------------------------------
// Flash attention, S^T form, x32 PV, s-split partials, 64-s double-buffer.
// 1024 blocks (qtile 128 x s-half x bh) x 4 waves; launch_bounds (256,5)
// (5 blocks/CU cap: 5x32KB = 160KB exact) for tail rebalance.
// XCD remap: bid%8 picks XCD; all 32 blocks of a head on one XCD -> K/V
// (512KB/head) L2-resident (proven: FETCH 12MB).
// 2-phase dbuf at constant 32KB: chunk = 64 s; Ks[2][64][64], Vs[2][64][64].
// QK s->m remap: A-frag lane reads K row 32*st32 + 8*(l16>>2) + 4F + (l16&3),
// with Ks chunk swizzle g(s)=(s&3)|(((s>>3)&1)<<2) keeping reads conflict-free.
// C-frag(quad,reg r) holds s = 32*st32 + 8*quad + 4F + r -> packs directly
// into the 16x16x32 PV B-operand. Fixed-max softmax: p = exp2(acc), acc init
// = -10*log2e, log2e baked into Q. Thin pack: plain __bf16 casts (compiler
// emits v_cvt_pk_bf16_f32). Partials (O bf16, lsum f32) additive across
// s-halves -> combined inside gemm_bt<1>'s A-staging.
// ---------------------------------------------------------------------------
__global__ __launch_bounds__(256, 5) void attn_kernel(
    const unsigned short* __restrict__ Qb,   // [32][2048][64]
    const unsigned short* __restrict__ Kb,   // [32][2048][64]
    const unsigned short* __restrict__ Vtb,  // [32][64][2048]
    unsigned short* __restrict__ OP,         // [2][4096][1024] bf16 partial O
    float* __restrict__ LS)                  // [2][32][2048] partial lsum
{
    __shared__ __attribute__((aligned(16))) unsigned short Ks[2 * 64 * 64];  // 16 KB
    __shared__ __attribute__((aligned(16))) unsigned short Vs[2 * 64 * 64];  // 16 KB

    const int tid  = threadIdx.x;
    const int lane = tid & 63;
    const int wid  = tid >> 6;
    const int quad = lane >> 4;
    const int l16  = lane & 15;
    const int l7   = l16 & 7;

    // XCD-clustering bijective remap over 1024 blocks:
    // bid -> (xcd c8, t); head = c8 + 8*(t>>5); u = t&31 -> (qtile, half)
    const int bid  = blockIdx.x + (blockIdx.y << 5);   // gridDim = (32, 32)
    const int c8   = bid & 7;
    const int t    = bid >> 3;           // 0..127
    const int hb   = c8 + ((t >> 5) << 3);
    const int u    = t & 31;
    const int qt16 = u >> 1;
    const int half = u & 1;
    const int q0   = qt16 * 128 + wid * 32;
    const int bq   = hb >> 4, hh = hb & 15;

    const unsigned short* Qh  = Qb  + (size_t)hb * 2048 * 64;
    const unsigned short* Kh  = Kb  + (size_t)hb * 2048 * 64;
    const unsigned short* Vth = Vtb + (size_t)hb * 64 * 2048;

    // Q B-frags: B[k=d][n=q], lane n=l16, k=quad*8+j; kh = d-half
    bf16x8 qf[2][2];
#pragma unroll
    for (int qt = 0; qt < 2; ++qt) {
        const unsigned short* qp = Qh + (size_t)(q0 + qt * 16 + l16) * 64 + quad * 8;
        qf[qt][0] = *(const bf16x8*)(qp);
        qf[qt][1] = *(const bf16x8*)(qp + 32);
    }

    f32x4 o[4][2];   // O^T accumulators: [hd-tile][q-tile]
#pragma unroll
    for (int ht = 0; ht < 4; ++ht)
#pragma unroll
        for (int qt = 0; qt < 2; ++qt)
            o[ht][qt] = (f32x4){0.f, 0.f, 0.f, 0.f};
    float lsum[2] = {0.f, 0.f};

    char* KsB = (char*)Ks;
    char* VsB = (char*)Vs;

    auto stageKV = [&](int kc, int buf) {
        char* ldsK = KsB + buf * 8192 + wid * 1024;
#pragma unroll
        for (int q = 0; q < 2; ++q) {
            int i   = q * 256 + tid;
            int row = i >> 3;
            int g   = (row & 3) | (((row >> 3) & 1) << 2);
            int ch  = (i & 7) ^ g;
            glds16(Kh + (size_t)(kc + row) * 64 + ch * 8, ldsK + q * 4096);
        }
        char* ldsV = VsB + buf * 8192 + wid * 1024;
#pragma unroll
        for (int q = 0; q < 2; ++q) {
            int i   = q * 256 + tid;
            int row = i >> 3;
            int ch  = (i & 7) ^ (row & 7);
            glds16(Vth + (size_t)row * 2048 + kc + ch * 8, ldsV + q * 4096);
        }
    };

    // lane-constant pieces of the fragment addresses
    const int base_row = 8 * (l16 >> 2) + (l16 & 3);   // K s->m remap, F=0
    const int kp0 = ((quad) ^ l7) * 16;                // d-half 0 chunk
    const int kp1 = ((4 + quad) ^ l7) * 16;            // d-half 1 chunk
    const int vrow = l16 * 128;

    const int kc0 = half * 1024;
    // prologue: stage first 64-s chunk into buf 0
    stageKV(kc0, 0);
    __syncthreads();

    for (int kc = kc0; kc < kc0 + 1024; kc += 64) {
        const int cur = (kc >> 6) & 1;
        if (kc + 64 < kc0 + 1024) stageKV(kc + 64, cur ^ 1);   // issue-early

        const char* KsC = KsB + cur * 8192;
        const char* VsC = VsB + cur * 8192;

#pragma unroll
        for (int st32 = 0; st32 < 2; ++st32) {   // 32 s per step
            const char* krb = KsC + (st32 * 32 + base_row) * 128;
            bf16x8 kf00 = *(const bf16x8*)(krb + kp0);
            bf16x8 kf01 = *(const bf16x8*)(krb + kp1);
            bf16x8 kf10 = *(const bf16x8*)(krb + 512 + kp0);   // F=1: +4 rows
            bf16x8 kf11 = *(const bf16x8*)(krb + 512 + kp1);

            const f32x4 mi = (f32x4){-FIXED_MAX_BITS, -FIXED_MAX_BITS,
                                     -FIXED_MAX_BITS, -FIXED_MAX_BITS};
            f32x4 s00 = mi, s01 = mi, s10 = mi, s11 = mi;  // [qt][F]
            s00 = __builtin_amdgcn_mfma_f32_16x16x32_bf16(kf00, qf[0][0], s00, 0, 0, 0);
            s00 = __builtin_amdgcn_mfma_f32_16x16x32_bf16(kf01, qf[0][1], s00, 0, 0, 0);
            s01 = __builtin_amdgcn_mfma_f32_16x16x32_bf16(kf10, qf[0][0], s01, 0, 0, 0);
            s01 = __builtin_amdgcn_mfma_f32_16x16x32_bf16(kf11, qf[0][1], s01, 0, 0, 0);
            s10 = __builtin_amdgcn_mfma_f32_16x16x32_bf16(kf00, qf[1][0], s10, 0, 0, 0);
            s10 = __builtin_amdgcn_mfma_f32_16x16x32_bf16(kf01, qf[1][1], s10, 0, 0, 0);
            s11 = __builtin_amdgcn_mfma_f32_16x16x32_bf16(kf10, qf[1][0], s11, 0, 0, 0);
            s11 = __builtin_amdgcn_mfma_f32_16x16x32_bf16(kf11, qf[1][1], s11, 0, 0, 0);

            bf16x8 p8[2];
#pragma unroll
            for (int qt = 0; qt < 2; ++qt) {
                const f32x4 sA = qt ? s10 : s00;
                const f32x4 sB = qt ? s11 : s01;
                float e0 = exp2_fast(sA[0]), e1 = exp2_fast(sA[1]);
                float e2 = exp2_fast(sA[2]), e3 = exp2_fast(sA[3]);
                float e4 = exp2_fast(sB[0]), e5 = exp2_fast(sB[1]);
                float e6 = exp2_fast(sB[2]), e7 = exp2_fast(sB[3]);
                lsum[qt] += ((e0 + e1) + (e2 + e3)) + ((e4 + e5) + (e6 + e7));
                // plain casts -> compiler emits packed v_cvt_pk_bf16_f32 (RNE)
                bf16x8 p;
                p[0] = (__bf16)e0; p[1] = (__bf16)e1;
                p[2] = (__bf16)e2; p[3] = (__bf16)e3;
                p[4] = (__bf16)e4; p[5] = (__bf16)e5;
                p[6] = (__bf16)e6; p[7] = (__bf16)e7;
                p8[qt] = p;
            }

            // V A-frags: one b128 per ht, chunk st32*4+quad (swizzled)
            const int voff = vrow + (((st32 * 4 + quad) ^ l7) * 16);
#pragma unroll
            for (int ht = 0; ht < 4; ++ht) {
                const bf16x8 vf = *(const bf16x8*)(VsC + voff + ht * 2048);
                o[ht][0] = __builtin_amdgcn_mfma_f32_16x16x32_bf16(vf, p8[0], o[ht][0], 0, 0, 0);
                o[ht][1] = __builtin_amdgcn_mfma_f32_16x16x32_bf16(vf, p8[1], o[ht][1], 0, 0, 0);
            }
        }
        __syncthreads();   // drains vmcnt(0): prefetch landed, buffers flip
    }

    // reduce lsum across quads (same l16 holds same q)
    float lt[2];
#pragma unroll
    for (int qt = 0; qt < 2; ++qt) {
        float s = lsum[qt];
        s += __shfl_xor(s, 16);
        s += __shfl_xor(s, 32);
        lt[qt] = s;
    }

    // write partial O (unnormalized) and partial lsum
    unsigned short* OPh = OP + (size_t)half * 4096 * 1024;
#pragma unroll
    for (int qt = 0; qt < 2; ++qt) {
        const size_t row = (size_t)(bq * 2048 + q0 + qt * 16 + l16);
#pragma unroll
        for (int ht = 0; ht < 4; ++ht) {
            ushort4 pk;
            pk.x = f2bf(o[ht][qt][0]);
            pk.y = f2bf(o[ht][qt][1]);
            pk.z = f2bf(o[ht][qt][2]);
            pk.w = f2bf(o[ht][qt][3]);
            *(ushort4*)(OPh + row * 1024 + hh * 64 + ht * 16 + quad * 4) = pk;
        }
    }
    if (quad == 0) {
        LS[half * 65536 + hb * 2048 + q0 + l16]      = lt[0];
        LS[half * 65536 + hb * 2048 + q0 + 16 + l16] = lt[1];
    }
}

// ---------------------------------------------------------------------------
// launch
// ---------------------------------------------------------------------------
extern "C" void kernel_launch(void* const* d_in, const int* in_sizes, int n_in,
                              void* d_out, int out_size, void* d_ws, size_t ws_size,
                              hipStream_t stream) {
    (void)in_sizes; (void)n_in; (void)out_size; (void)ws_size;

    const float* x  = (const float*)d_in[0];
    const float* Wq = (const float*)d_in[1];
    const float* bq = (const float*)d_in[2];
    const float* Wk = (const float*)d_in[3];
    const float* bk = (const float*)d_in[4];
    const float* Wv = (const float*)d_in[5];
    const float* bv = (const float*)d_in[6];
    const float* Wo = (const float*)d_in[7];
    const float* bo = (const float*)d_in[8];

    char* ws = (char*)d_ws;
    const size_t MB = 1024 * 1024;
    unsigned short* xb    = (unsigned short*)(ws + 0);        //  8 MB [4096][1024]
    unsigned short* Wqb   = (unsigned short*)(ws + 8  * MB);  //  2 MB
    unsigned short* Wkb   = (unsigned short*)(ws + 10 * MB);
    unsigned short* Wvb   = (unsigned short*)(ws + 12 * MB);
    unsigned short* Wob   = (unsigned short*)(ws + 14 * MB);
    unsigned short* Qb    = (unsigned short*)(ws + 16 * MB);  //  8 MB [32][2048][64]
    unsigned short* Kb    = (unsigned short*)(ws + 24 * MB);  //  8 MB
    unsigned short* Vtb   = (unsigned short*)(ws + 32 * MB);  //  8 MB [32][64][2048]
    unsigned short* OP    = (unsigned short*)(ws + 48 * MB);  // 16 MB [2][4096][1024]
    float*          LSb   = (float*)(ws + 64 * MB);           // 512 KB [2][32][2048]

    cvt_all<<<dim3(1024), dim3(256), 0, stream>>>(
        x, Wq, Wk, Wv, Wo, xb, Wqb, Wkb, Wvb, Wob);

    gemm_bt<0><<<dim3(32, 24), dim3(256), 0, stream>>>(
        xb, Wqb, Wkb, Wvb, bq, bk, bv, Qb, Kb, Vtb, nullptr);

    attn_kernel<<<dim3(32, 32), dim3(256), 0, stream>>>(Qb, Kb, Vtb, OP, LSb);

    // output GEMM with fused s-half combine: A = OP (both halves), b1 = LS
    gemm_bt<1><<<dim3(64, 8), dim3(256), 0, stream>>>(
        OP, Wob, nullptr, nullptr, bo, LSb, nullptr,
        nullptr, nullptr, nullptr, (float*)d_out);
}

// Round 7
// 195.759 us; speedup vs baseline: 1.3277x; 1.3277x over previous
//
#include <hip/hip_runtime.h>
#include <stdint.h>

// ---------------------------------------------------------------------------
// MultiHeadAttention  B=2 S=2048 D=1024 H=16 HD=64   (fp32 in/out, bf16 MFMA)
// convert->bf16, fused QKV GEMM, flash attention (S^T form, x32 PV, s-split
// partials), output GEMM with FUSED partial-combine (attn_reduce deleted).
// Round change vs r6: REVERT attn __launch_bounds__ to (256,4). The (256,5)
// cap shrank VGPR 60->48 and spilled the O accumulators to scratch
// (WRITE_SIZE 16.9MB -> 179MB, dur 46 -> 113us). Everything else (gemm1
// fused combine, s-split, XCD remap, 64-s dbuf) kept from r6.
// ---------------------------------------------------------------------------

typedef __bf16 bf16x8 __attribute__((ext_vector_type(8)));
typedef float  f32x4  __attribute__((ext_vector_type(4)));

#define LOG2E 1.44269504088896f
#define FIXED_MAX_BITS 14.4269504088896f   /* 10 nats * log2(e) */

__device__ __forceinline__ unsigned short f2bf(float f) {
    union { float f; unsigned u; } v; v.f = f;
    unsigned r = v.u + 0x7FFFu + ((v.u >> 16) & 1u);   // round-to-nearest-even
    return (unsigned short)(r >> 16);
}

__device__ __forceinline__ float exp2_fast(float x) {
#if __has_builtin(__builtin_amdgcn_exp2f)
    return __builtin_amdgcn_exp2f(x);
#else
    return __expf(x * 0.69314718056f);
#endif
}

// combine two bf16 pairs (packed in u32) : ((a+b)*rl) -> packed bf16 pair
__device__ __forceinline__ unsigned comb2(unsigned wa, unsigned wb, float rl) {
    union { unsigned u; float f; } la, ha, lb, hb;
    la.u = wa << 16; ha.u = wa & 0xffff0000u;
    lb.u = wb << 16; hb.u = wb & 0xffff0000u;
    float lo = (la.f + lb.f) * rl;
    float hi = (ha.f + hb.f) * rl;
    __bf16 l = (__bf16)lo, h = (__bf16)hi;
    unsigned short lu = __builtin_bit_cast(unsigned short, l);
    unsigned short hu = __builtin_bit_cast(unsigned short, h);
    return (unsigned)lu | ((unsigned)hu << 16);
}

// async global->LDS, 16B per lane; lds dest = wave-uniform base + lane*16
__device__ __forceinline__ void glds16(const void* g, void* l) {
    __builtin_amdgcn_global_load_lds(
        (__attribute__((address_space(1))) void*)(g),
        (__attribute__((address_space(3))) void*)(l),
        16, 0, 0);
}

// ---------------------------------------------------------------------------
// fp32 -> bf16 convert: x (1M float4) + 4 weights (256K float4 each), 1 launch
// ---------------------------------------------------------------------------
__global__ __launch_bounds__(256) void cvt_all(
    const float* __restrict__ x,  const float* __restrict__ Wq,
    const float* __restrict__ Wk, const float* __restrict__ Wv,
    const float* __restrict__ Wo,
    unsigned short* __restrict__ xb,  unsigned short* __restrict__ Wqb,
    unsigned short* __restrict__ Wkb, unsigned short* __restrict__ Wvb,
    unsigned short* __restrict__ Wob)
{
    const int stride = gridDim.x * blockDim.x;
    for (int i = blockIdx.x * blockDim.x + threadIdx.x; i < 2097152; i += stride) {
        const float* src; unsigned short* dst; int j;
        if (i < 1048576) { src = x; dst = xb; j = i; }
        else {
            int t = (i - 1048576) >> 18; j = (i - 1048576) & 262143;
            src = (t == 0) ? Wq : (t == 1) ? Wk : (t == 2) ? Wv : Wo;
            dst = (t == 0) ? Wqb : (t == 1) ? Wkb : (t == 2) ? Wvb : Wob;
        }
        float4 v = ((const float4*)src)[j];
        ushort4 o;
        o.x = f2bf(v.x); o.y = f2bf(v.y); o.z = f2bf(v.z); o.w = f2bf(v.w);
        ((ushort4*)dst)[j] = o;
    }
}

// ---------------------------------------------------------------------------
// GEMM  C[m][n] = sum_k A[m][k] * W[n][k]  (+bias), 2-phase LDS double-buffer
// MODE 0: A = bf16 activations, glds16 staging, 3 projections.
// MODE 1: A = (OP0 + OP1) * rl fused on the fly (attn partial combine);
//         A-staging = reg-load (issue-early) + combine + ds_write (commit
//         after compute). b1 carries LS (partial lsums). W0 = Wo.
// ---------------------------------------------------------------------------
template <int MODE>
__global__ __launch_bounds__(256) void gemm_bt(
    const unsigned short* __restrict__ A,
    const unsigned short* __restrict__ W0,
    const unsigned short* __restrict__ W1,
    const unsigned short* __restrict__ W2,
    const float* __restrict__ b0,
    const float* __restrict__ b1,
    const float* __restrict__ b2,
    unsigned short* __restrict__ outQ,
    unsigned short* __restrict__ outK,
    unsigned short* __restrict__ outV,
    float* __restrict__ outF)
{
    constexpr int BM = (MODE == 0) ? 128 : 64;
    constexpr int FM = BM / 32;
    constexpr int RA = BM / 32;

    __shared__ __attribute__((aligned(16))) unsigned short As[2 * BM * 64];
    __shared__ __attribute__((aligned(16))) unsigned short Bs[2 * 128 * 64];
    __shared__ float Lrec[(MODE == 1) ? 1024 : 4];   // 1/(LS0+LS1) per (row,head)

    const int tid  = threadIdx.x;
    const int lane = tid & 63;
    const int wid  = tid >> 6;
    const int quad = lane >> 4;
    const int l16  = lane & 15;

    const int m0 = blockIdx.x * BM;

    const unsigned short* W;
    const float* bias;
    int proj, n0;
    if (MODE == 0) {
        proj = blockIdx.y >> 3;
        n0   = (blockIdx.y & 7) * 128;
        W    = (proj == 0) ? W0 : (proj == 1) ? W1 : W2;
        bias = (proj == 0) ? b0 : (proj == 1) ? b1 : b2;
    } else {
        proj = 0;
        n0   = blockIdx.y * 128;
        W    = W0;
        bias = b0;
    }

    const int wm = (wid >> 1) * (BM / 2);
    const int wn = (wid & 1) * 64;

    f32x4 acc[FM][4];
#pragma unroll
    for (int i = 0; i < FM; ++i)
#pragma unroll
        for (int j = 0; j < 4; ++j)
            acc[i][j] = (f32x4){0.f, 0.f, 0.f, 0.f};

    char* AsB = (char*)As;
    char* BsB = (char*)Bs;

    // ---- staging helpers -------------------------------------------------
    auto stageB = [&](int k0, int buf) {
        char* ldsB = BsB + buf * 16384 + wid * 1024;
#pragma unroll
        for (int q = 0; q < 4; ++q) {
            int i   = q * 256 + tid;
            int row = i >> 3;
            int sc  = (i & 7) ^ (row & 7);
            glds16(W + (size_t)(n0 + row) * 1024 + k0 + sc * 8, ldsB + q * 4096);
        }
    };
    auto stageA_g = [&](int k0, int buf) {     // MODE 0 path (glds16)
        char* ldsA = AsB + buf * (BM * 128) + wid * 1024;
#pragma unroll
        for (int q = 0; q < RA; ++q) {
            int i   = q * 256 + tid;
            int row = i >> 3;
            int sc  = (i & 7) ^ (row & 7);
            glds16(A + (size_t)(m0 + row) * 1024 + k0 + sc * 8, ldsA + q * 4096);
        }
    };

    // MODE 1: A reg-staging state (2 rounds x 16B from each half)
    uint4 ar0[2], ar1[2];
    float arl[2];
    auto aload = [&](int k0) {
#pragma unroll
        for (int q = 0; q < 2; ++q) {
            int i   = q * 256 + tid;
            int row = i >> 3;
            int sc  = (i & 7) ^ (row & 7);
            const size_t gof = (size_t)(m0 + row) * 1024 + k0 + sc * 8;
            ar0[q] = *(const uint4*)(A + gof);
            ar1[q] = *(const uint4*)(A + 4194304 + gof);
            arl[q] = Lrec[row * 16 + (k0 >> 6)];
        }
    };
    auto acommit = [&](int buf) {
#pragma unroll
        for (int q = 0; q < 2; ++q) {
            int i = q * 256 + tid;
            uint4 o;
            o.x = comb2(ar0[q].x, ar1[q].x, arl[q]);
            o.y = comb2(ar0[q].y, ar1[q].y, arl[q]);
            o.z = comb2(ar0[q].z, ar1[q].z, arl[q]);
            o.w = comb2(ar0[q].w, ar1[q].w, arl[q]);
            *(uint4*)(AsB + buf * (BM * 128) + i * 16) = o;
        }
    };

    // ---- prologue --------------------------------------------------------
    if constexpr (MODE == 1) {
        // per-block reciprocal-lsum table: rows m0..m0+63 x 16 heads
        const float* LSp = b1;
        const int bq16 = (m0 >> 11) << 4;
        const int mq0  = m0 & 2047;
#pragma unroll
        for (int j = 0; j < 4; ++j) {
            int idx = j * 256 + tid;
            int rr  = idx >> 4, h = idx & 15;
            int off = (bq16 + h) * 2048 + mq0 + rr;
            Lrec[idx] = 1.0f / (LSp[off] + LSp[65536 + off]);
        }
        __syncthreads();
        aload(0);
        acommit(0);
        stageB(0, 0);
    } else {
        stageA_g(0, 0);
        stageB(0, 0);
    }
    __syncthreads();

    // ---- main loop -------------------------------------------------------
    for (int k0 = 0; k0 < 1024; k0 += 64) {
        const int cur = (k0 >> 6) & 1;
        const bool pf = (k0 + 64 < 1024);
        if (pf) {
            if constexpr (MODE == 1) {
                aload(k0 + 64);             // issue-early: hides under MFMA
                stageB(k0 + 64, cur ^ 1);
            } else {
                stageA_g(k0 + 64, cur ^ 1);
                stageB(k0 + 64, cur ^ 1);
            }
        }

        const char* AsC = AsB + cur * (BM * 128);
        const char* BsC = BsB + cur * 16384;

#pragma unroll
        for (int kh = 0; kh < 2; ++kh) {
            bf16x8 af[FM], bfr[4];
#pragma unroll
            for (int t = 0; t < FM; ++t) {
                int r = wm + t * 16 + l16;
                int c = (kh * 4 + quad) ^ (r & 7);
                af[t] = *(const bf16x8*)(AsC + r * 128 + c * 16);
            }
#pragma unroll
            for (int t = 0; t < 4; ++t) {
                int r = wn + t * 16 + l16;
                int c = (kh * 4 + quad) ^ (r & 7);
                bfr[t] = *(const bf16x8*)(BsC + r * 128 + c * 16);
            }
#pragma unroll
            for (int i = 0; i < FM; ++i)
#pragma unroll
                for (int j = 0; j < 4; ++j)
                    acc[i][j] = __builtin_amdgcn_mfma_f32_16x16x32_bf16(
                        af[i], bfr[j], acc[i][j], 0, 0, 0);
        }

        if constexpr (MODE == 1) {
            if (pf) acommit(cur ^ 1);       // combine + ds_write after compute
        }
        __syncthreads();   // drains vmcnt/lgkm: prefetch landed, buffers flip
    }

    // ---- epilogue --------------------------------------------------------
#pragma unroll
    for (int i = 0; i < FM; ++i) {
        const int mrow0 = m0 + wm + i * 16 + quad * 4;
#pragma unroll
        for (int j = 0; j < 4; ++j) {
            const int n  = n0 + wn + j * 16 + l16;
            const float bb = bias[n];
            if (MODE == 1) {
#pragma unroll
                for (int r = 0; r < 4; ++r)
                    outF[(size_t)(mrow0 + r) * 1024 + n] = acc[i][j][r] + bb;
            } else {
                const int h = n >> 6, hd = n & 63;
                if (proj == 2) {
                    const int b = mrow0 >> 11, s = mrow0 & 2047;
                    ushort4 pk;
                    pk.x = f2bf(acc[i][j][0] + bb);
                    pk.y = f2bf(acc[i][j][1] + bb);
                    pk.z = f2bf(acc[i][j][2] + bb);
                    pk.w = f2bf(acc[i][j][3] + bb);
                    *(ushort4*)(outV + ((size_t)((b * 16 + h) * 64 + hd)) * 2048 + s) = pk;
                } else {
                    unsigned short* dst = (proj == 0) ? outQ : outK;
                    const float scl = (proj == 0) ? (0.125f * LOG2E) : 1.0f;
#pragma unroll
                    for (int r = 0; r < 4; ++r) {
                        const int m = mrow0 + r;
                        const int b = m >> 11, s = m & 2047;
                        dst[((size_t)((b * 16 + h) * 2048 + s)) * 64 + hd] =
                            f2bf((acc[i][j][r] + bb) * scl);
                    }
                }
            }
        }
    }
}

// ---------------------------------------------------------------------------
// Flash attention, S^T form, x32 PV, s-split partials, 64-s double-buffer.
// 1024 blocks (qtile 128 x s-half x bh) x 4 waves = 4 blocks/CU resident.
// launch_bounds (256,4): (256,5) in r6 spilled (VGPR 60->48, 179MB scratch).
// XCD remap: bid%8 picks XCD; all 32 blocks of a head on one XCD -> K/V
// (512KB/head) L2-resident (proven: FETCH 12MB).
// 2-phase dbuf at constant 32KB: chunk = 64 s; Ks[2][64][64], Vs[2][64][64].
// QK s->m remap: A-frag lane reads K row 32*st32 + 8*(l16>>2) + 4F + (l16&3),
// with Ks chunk swizzle g(s)=(s&3)|(((s>>3)&1)<<2) keeping reads conflict-free.
// C-frag(quad,reg r) holds s = 32*st32 + 8*quad + 4F + r -> packs directly
// into the 16x16x32 PV B-operand. Fixed-max softmax: p = exp2(acc), acc init
// = -10*log2e, log2e baked into Q. Thin pack: plain __bf16 casts (compiler
// emits v_cvt_pk_bf16_f32). Partials (O bf16, lsum f32) additive across
// s-halves -> combined inside gemm_bt<1>'s A-staging.
// ---------------------------------------------------------------------------
__global__ __launch_bounds__(256, 4) void attn_kernel(
    const unsigned short* __restrict__ Qb,   // [32][2048][64]
    const unsigned short* __restrict__ Kb,   // [32][2048][64]
    const unsigned short* __restrict__ Vtb,  // [32][64][2048]
    unsigned short* __restrict__ OP,         // [2][4096][1024] bf16 partial O
    float* __restrict__ LS)                  // [2][32][2048] partial lsum
{
    __shared__ __attribute__((aligned(16))) unsigned short Ks[2 * 64 * 64];  // 16 KB
    __shared__ __attribute__((aligned(16))) unsigned short Vs[2 * 64 * 64];  // 16 KB

    const int tid  = threadIdx.x;
    const int lane = tid & 63;
    const int wid  = tid >> 6;
    const int quad = lane >> 4;
    const int l16  = lane & 15;
    const int l7   = l16 & 7;

    // XCD-clustering bijective remap over 1024 blocks:
    // bid -> (xcd c8, t); head = c8 + 8*(t>>5); u = t&31 -> (qtile, half)
    const int bid  = blockIdx.x + (blockIdx.y << 5);   // gridDim = (32, 32)
    const int c8   = bid & 7;
    const int t    = bid >> 3;           // 0..127
    const int hb   = c8 + ((t >> 5) << 3);
    const int u    = t & 31;
    const int qt16 = u >> 1;
    const int half = u & 1;
    const int q0   = qt16 * 128 + wid * 32;
    const int bq   = hb >> 4, hh = hb & 15;

    const unsigned short* Qh  = Qb  + (size_t)hb * 2048 * 64;
    const unsigned short* Kh  = Kb  + (size_t)hb * 2048 * 64;
    const unsigned short* Vth = Vtb + (size_t)hb * 64 * 2048;

    // Q B-frags: B[k=d][n=q], lane n=l16, k=quad*8+j; kh = d-half
    bf16x8 qf[2][2];
#pragma unroll
    for (int qt = 0; qt < 2; ++qt) {
        const unsigned short* qp = Qh + (size_t)(q0 + qt * 16 + l16) * 64 + quad * 8;
        qf[qt][0] = *(const bf16x8*)(qp);
        qf[qt][1] = *(const bf16x8*)(qp + 32);
    }

    f32x4 o[4][2];   // O^T accumulators: [hd-tile][q-tile]
#pragma unroll
    for (int ht = 0; ht < 4; ++ht)
#pragma unroll
        for (int qt = 0; qt < 2; ++qt)
            o[ht][qt] = (f32x4){0.f, 0.f, 0.f, 0.f};
    float lsum[2] = {0.f, 0.f};

    char* KsB = (char*)Ks;
    char* VsB = (char*)Vs;

    auto stageKV = [&](int kc, int buf) {
        char* ldsK = KsB + buf * 8192 + wid * 1024;
#pragma unroll
        for (int q = 0; q < 2; ++q) {
            int i   = q * 256 + tid;
            int row = i >> 3;
            int g   = (row & 3) | (((row >> 3) & 1) << 2);
            int ch  = (i & 7) ^ g;
            glds16(Kh + (size_t)(kc + row) * 64 + ch * 8, ldsK + q * 4096);
        }
        char* ldsV = VsB + buf * 8192 + wid * 1024;
#pragma unroll
        for (int q = 0; q < 2; ++q) {
            int i   = q * 256 + tid;
            int row = i >> 3;
            int ch  = (i & 7) ^ (row & 7);
            glds16(Vth + (size_t)row * 2048 + kc + ch * 8, ldsV + q * 4096);
        }
    };

    // lane-constant pieces of the fragment addresses
    const int base_row = 8 * (l16 >> 2) + (l16 & 3);   // K s->m remap, F=0
    const int kp0 = ((quad) ^ l7) * 16;                // d-half 0 chunk
    const int kp1 = ((4 + quad) ^ l7) * 16;            // d-half 1 chunk
    const int vrow = l16 * 128;

    const int kc0 = half * 1024;
    // prologue: stage first 64-s chunk into buf 0
    stageKV(kc0, 0);
    __syncthreads();

    for (int kc = kc0; kc < kc0 + 1024; kc += 64) {
        const int cur = (kc >> 6) & 1;
        if (kc + 64 < kc0 + 1024) stageKV(kc + 64, cur ^ 1);   // issue-early

        const char* KsC = KsB + cur * 8192;
        const char* VsC = VsB + cur * 8192;

#pragma unroll
        for (int st32 = 0; st32 < 2; ++st32) {   // 32 s per step
            const char* krb = KsC + (st32 * 32 + base_row) * 128;
            bf16x8 kf00 = *(const bf16x8*)(krb + kp0);
            bf16x8 kf01 = *(const bf16x8*)(krb + kp1);
            bf16x8 kf10 = *(const bf16x8*)(krb + 512 + kp0);   // F=1: +4 rows
            bf16x8 kf11 = *(const bf16x8*)(krb + 512 + kp1);

            const f32x4 mi = (f32x4){-FIXED_MAX_BITS, -FIXED_MAX_BITS,
                                     -FIXED_MAX_BITS, -FIXED_MAX_BITS};
            f32x4 s00 = mi, s01 = mi, s10 = mi, s11 = mi;  // [qt][F]
            s00 = __builtin_amdgcn_mfma_f32_16x16x32_bf16(kf00, qf[0][0], s00, 0, 0, 0);
            s00 = __builtin_amdgcn_mfma_f32_16x16x32_bf16(kf01, qf[0][1], s00, 0, 0, 0);
            s01 = __builtin_amdgcn_mfma_f32_16x16x32_bf16(kf10, qf[0][0], s01, 0, 0, 0);
            s01 = __builtin_amdgcn_mfma_f32_16x16x32_bf16(kf11, qf[0][1], s01, 0, 0, 0);
            s10 = __builtin_amdgcn_mfma_f32_16x16x32_bf16(kf00, qf[1][0], s10, 0, 0, 0);
            s10 = __builtin_amdgcn_mfma_f32_16x16x32_bf16(kf01, qf[1][1], s10, 0, 0, 0);
            s11 = __builtin_amdgcn_mfma_f32_16x16x32_bf16(kf10, qf[1][0], s11, 0, 0, 0);
            s11 = __builtin_amdgcn_mfma_f32_16x16x32_bf16(kf11, qf[1][1], s11, 0, 0, 0);

            bf16x8 p8[2];
#pragma unroll
            for (int qt = 0; qt < 2; ++qt) {
                const f32x4 sA = qt ? s10 : s00;
                const f32x4 sB = qt ? s11 : s01;
                float e0 = exp2_fast(sA[0]), e1 = exp2_fast(sA[1]);
                float e2 = exp2_fast(sA[2]), e3 = exp2_fast(sA[3]);
                float e4 = exp2_fast(sB[0]), e5 = exp2_fast(sB[1]);
                float e6 = exp2_fast(sB[2]), e7 = exp2_fast(sB[3]);
                lsum[qt] += ((e0 + e1) + (e2 + e3)) + ((e4 + e5) + (e6 + e7));
                // plain casts -> compiler emits packed v_cvt_pk_bf16_f32 (RNE)
                bf16x8 p;
                p[0] = (__bf16)e0; p[1] = (__bf16)e1;
                p[2] = (__bf16)e2; p[3] = (__bf16)e3;
                p[4] = (__bf16)e4; p[5] = (__bf16)e5;
                p[6] = (__bf16)e6; p[7] = (__bf16)e7;
                p8[qt] = p;
            }

            // V A-frags: one b128 per ht, chunk st32*4+quad (swizzled)
            const int voff = vrow + (((st32 * 4 + quad) ^ l7) * 16);
#pragma unroll
            for (int ht = 0; ht < 4; ++ht) {
                const bf16x8 vf = *(const bf16x8*)(VsC + voff + ht * 2048);
                o[ht][0] = __builtin_amdgcn_mfma_f32_16x16x32_bf16(vf, p8[0], o[ht][0], 0, 0, 0);
                o[ht][1] = __builtin_amdgcn_mfma_f32_16x16x32_bf16(vf, p8[1], o[ht][1], 0, 0, 0);
            }
        }
        __syncthreads();   // drains vmcnt(0): prefetch landed, buffers flip
    }

    // reduce lsum across quads (same l16 holds same q)
    float lt[2];
#pragma unroll
    for (int qt = 0; qt < 2; ++qt) {
        float s = lsum[qt];
        s += __shfl_xor(s, 16);
        s += __shfl_xor(s, 32);
        lt[qt] = s;
    }

    // write partial O (unnormalized) and partial lsum
    unsigned short* OPh = OP + (size_t)half * 4096 * 1024;
#pragma unroll
    for (int qt = 0; qt < 2; ++qt) {
        const size_t row = (size_t)(bq * 2048 + q0 + qt * 16 + l16);
#pragma unroll
        for (int ht = 0; ht < 4; ++ht) {
            ushort4 pk;
            pk.x = f2bf(o[ht][qt][0]);
            pk.y = f2bf(o[ht][qt][1]);
            pk.z = f2bf(o[ht][qt][2]);
            pk.w = f2bf(o[ht][qt][3]);
            *(ushort4*)(OPh + row * 1024 + hh * 64 + ht * 16 + quad * 4) = pk;
        }
    }
    if (quad == 0) {
        LS[half * 65536 + hb * 2048 + q0 + l16]      = lt[0];
        LS[half * 65536 + hb * 2048 + q0 + 16 + l16] = lt[1];
    }
}

// ---------------------------------------------------------------------------
// launch
// ---------------------------------------------------------------------------
extern "C" void kernel_launch(void* const* d_in, const int* in_sizes, int n_in,
                              void* d_out, int out_size, void* d_ws, size_t ws_size,
                              hipStream_t stream) {
    (void)in_sizes; (void)n_in; (void)out_size; (void)ws_size;

    const float* x  = (const float*)d_in[0];
    const float* Wq = (const float*)d_in[1];
    const float* bq = (const float*)d_in[2];
    const float* Wk = (const float*)d_in[3];
    const float* bk = (const float*)d_in[4];
    const float* Wv = (const float*)d_in[5];
    const float* bv = (const float*)d_in[6];
    const float* Wo = (const float*)d_in[7];
    const float* bo = (const float*)d_in[8];

    char* ws = (char*)d_ws;
    const size_t MB = 1024 * 1024;
    unsigned short* xb    = (unsigned short*)(ws + 0);        //  8 MB [4096][1024]
    unsigned short* Wqb   = (unsigned short*)(ws + 8  * MB);  //  2 MB
    unsigned short* Wkb   = (unsigned short*)(ws + 10 * MB);
    unsigned short* Wvb   = (unsigned short*)(ws + 12 * MB);
    unsigned short* Wob   = (unsigned short*)(ws + 14 * MB);
    unsigned short* Qb    = (unsigned short*)(ws + 16 * MB);  //  8 MB [32][2048][64]
    unsigned short* Kb    = (unsigned short*)(ws + 24 * MB);  //  8 MB
    unsigned short* Vtb   = (unsigned short*)(ws + 32 * MB);  //  8 MB [32][64][2048]
    unsigned short* OP    = (unsigned short*)(ws + 48 * MB);  // 16 MB [2][4096][1024]
    float*          LSb   = (float*)(ws + 64 * MB);           // 512 KB [2][32][2048]

    cvt_all<<<dim3(1024), dim3(256), 0, stream>>>(
        x, Wq, Wk, Wv, Wo, xb, Wqb, Wkb, Wvb, Wob);

    gemm_bt<0><<<dim3(32, 24), dim3(256), 0, stream>>>(
        xb, Wqb, Wkb, Wvb, bq, bk, bv, Qb, Kb, Vtb, nullptr);

    attn_kernel<<<dim3(32, 32), dim3(256), 0, stream>>>(Qb, Kb, Vtb, OP, LSb);

    // output GEMM with fused s-half combine: A = OP (both halves), b1 = LS
    gemm_bt<1><<<dim3(64, 8), dim3(256), 0, stream>>>(
        OP, Wob, nullptr, nullptr, bo, LSb, nullptr,
        nullptr, nullptr, nullptr, (float*)d_out);
}

// Round 8
// 182.518 us; speedup vs baseline: 1.4241x; 1.0725x over previous
//
#include <hip/hip_runtime.h>
#include <stdint.h>

// ---------------------------------------------------------------------------
// MultiHeadAttention  B=2 S=2048 D=1024 H=16 HD=64   (fp32 in/out, bf16 MFMA)
// convert->bf16, fused QKV GEMM, flash attention (S^T form, x32 PV, s-split
// ACROSS WAVES of one block with in-LDS f32 combine), output GEMM.
// Round change vs r7: gemm1 fused combine was net-negative (+12us on gemm1
// vs -7us reduce); relocate the s-half combine INTO attn: 512-thread blocks,
// waves 0-3 = s-half 0, waves 4-7 = s-half 1, each group has its own 32KB
// K/V dbuf (64KB -> 2 blocks/CU x 8 waves = 16 waves/CU, same TLP as r5).
// Epilogue: group1 writes f32 partials to LDS ([128][65] pad, conflict-free),
// barrier, group0 combines + normalizes + writes attnb directly. attn_reduce
// kernel, OP (16MB) and LS round-trips all deleted; gemm1 reverts to r5
// glds16 staging from attnb. Combine now in f32 (accuracy >= r5).
// ---------------------------------------------------------------------------

typedef __bf16 bf16x8 __attribute__((ext_vector_type(8)));
typedef float  f32x4  __attribute__((ext_vector_type(4)));

#define LOG2E 1.44269504088896f
#define FIXED_MAX_BITS 14.4269504088896f   /* 10 nats * log2(e) */

__device__ __forceinline__ unsigned short f2bf(float f) {
    union { float f; unsigned u; } v; v.f = f;
    unsigned r = v.u + 0x7FFFu + ((v.u >> 16) & 1u);   // round-to-nearest-even
    return (unsigned short)(r >> 16);
}

__device__ __forceinline__ float exp2_fast(float x) {
#if __has_builtin(__builtin_amdgcn_exp2f)
    return __builtin_amdgcn_exp2f(x);
#else
    return __expf(x * 0.69314718056f);
#endif
}

// async global->LDS, 16B per lane; lds dest = wave-uniform base + lane*16
__device__ __forceinline__ void glds16(const void* g, void* l) {
    __builtin_amdgcn_global_load_lds(
        (__attribute__((address_space(1))) void*)(g),
        (__attribute__((address_space(3))) void*)(l),
        16, 0, 0);
}

// ---------------------------------------------------------------------------
// fp32 -> bf16 convert: x (1M float4) + 4 weights (256K float4 each), 1 launch
// ---------------------------------------------------------------------------
__global__ __launch_bounds__(256) void cvt_all(
    const float* __restrict__ x,  const float* __restrict__ Wq,
    const float* __restrict__ Wk, const float* __restrict__ Wv,
    const float* __restrict__ Wo,
    unsigned short* __restrict__ xb,  unsigned short* __restrict__ Wqb,
    unsigned short* __restrict__ Wkb, unsigned short* __restrict__ Wvb,
    unsigned short* __restrict__ Wob)
{
    const int stride = gridDim.x * blockDim.x;
    for (int i = blockIdx.x * blockDim.x + threadIdx.x; i < 2097152; i += stride) {
        const float* src; unsigned short* dst; int j;
        if (i < 1048576) { src = x; dst = xb; j = i; }
        else {
            int t = (i - 1048576) >> 18; j = (i - 1048576) & 262143;
            src = (t == 0) ? Wq : (t == 1) ? Wk : (t == 2) ? Wv : Wo;
            dst = (t == 0) ? Wqb : (t == 1) ? Wkb : (t == 2) ? Wvb : Wob;
        }
        float4 v = ((const float4*)src)[j];
        ushort4 o;
        o.x = f2bf(v.x); o.y = f2bf(v.y); o.z = f2bf(v.z); o.w = f2bf(v.w);
        ((ushort4*)dst)[j] = o;
    }
}

// ---------------------------------------------------------------------------
// GEMM  C[m][n] = sum_k A[m][k] * W[n][k]  (+bias), 2-phase LDS double-buffer
// (r5 form: both modes stage A via glds16; MODE1 A = attnb)
// ---------------------------------------------------------------------------
template <int MODE>
__global__ __launch_bounds__(256) void gemm_bt(
    const unsigned short* __restrict__ A,
    const unsigned short* __restrict__ W0,
    const unsigned short* __restrict__ W1,
    const unsigned short* __restrict__ W2,
    const float* __restrict__ b0,
    const float* __restrict__ b1,
    const float* __restrict__ b2,
    unsigned short* __restrict__ outQ,
    unsigned short* __restrict__ outK,
    unsigned short* __restrict__ outV,
    float* __restrict__ outF)
{
    constexpr int BM = (MODE == 0) ? 128 : 64;
    constexpr int FM = BM / 32;
    constexpr int RA = BM / 32;

    __shared__ __attribute__((aligned(16))) unsigned short As[2 * BM * 64];
    __shared__ __attribute__((aligned(16))) unsigned short Bs[2 * 128 * 64];

    const int tid  = threadIdx.x;
    const int lane = tid & 63;
    const int wid  = tid >> 6;
    const int quad = lane >> 4;
    const int l16  = lane & 15;

    const int m0 = blockIdx.x * BM;

    const unsigned short* W;
    const float* bias;
    int proj, n0;
    if (MODE == 0) {
        proj = blockIdx.y >> 3;
        n0   = (blockIdx.y & 7) * 128;
        W    = (proj == 0) ? W0 : (proj == 1) ? W1 : W2;
        bias = (proj == 0) ? b0 : (proj == 1) ? b1 : b2;
    } else {
        proj = 0;
        n0   = blockIdx.y * 128;
        W    = W0;
        bias = b0;
    }

    const int wm = (wid >> 1) * (BM / 2);
    const int wn = (wid & 1) * 64;

    f32x4 acc[FM][4];
#pragma unroll
    for (int i = 0; i < FM; ++i)
#pragma unroll
        for (int j = 0; j < 4; ++j)
            acc[i][j] = (f32x4){0.f, 0.f, 0.f, 0.f};

    char* AsB = (char*)As;
    char* BsB = (char*)Bs;

    auto stageAB = [&](int k0, int buf) {
        char* ldsA = AsB + buf * (BM * 128) + wid * 1024;
        char* ldsB = BsB + buf * 16384 + wid * 1024;
#pragma unroll
        for (int q = 0; q < RA; ++q) {
            int i   = q * 256 + tid;
            int row = i >> 3;
            int sc  = (i & 7) ^ (row & 7);
            glds16(A + (size_t)(m0 + row) * 1024 + k0 + sc * 8, ldsA + q * 4096);
        }
#pragma unroll
        for (int q = 0; q < 4; ++q) {
            int i   = q * 256 + tid;
            int row = i >> 3;
            int sc  = (i & 7) ^ (row & 7);
            glds16(W + (size_t)(n0 + row) * 1024 + k0 + sc * 8, ldsB + q * 4096);
        }
    };

    // prologue: stage first K-tile into buf 0
    stageAB(0, 0);
    __syncthreads();

    for (int k0 = 0; k0 < 1024; k0 += 64) {
        const int cur = (k0 >> 6) & 1;
        if (k0 + 64 < 1024) stageAB(k0 + 64, cur ^ 1);   // issue-early prefetch

        const char* AsC = AsB + cur * (BM * 128);
        const char* BsC = BsB + cur * 16384;

#pragma unroll
        for (int kh = 0; kh < 2; ++kh) {
            bf16x8 af[FM], bfr[4];
#pragma unroll
            for (int t = 0; t < FM; ++t) {
                int r = wm + t * 16 + l16;
                int c = (kh * 4 + quad) ^ (r & 7);
                af[t] = *(const bf16x8*)(AsC + r * 128 + c * 16);
            }
#pragma unroll
            for (int t = 0; t < 4; ++t) {
                int r = wn + t * 16 + l16;
                int c = (kh * 4 + quad) ^ (r & 7);
                bfr[t] = *(const bf16x8*)(BsC + r * 128 + c * 16);
            }
#pragma unroll
            for (int i = 0; i < FM; ++i)
#pragma unroll
                for (int j = 0; j < 4; ++j)
                    acc[i][j] = __builtin_amdgcn_mfma_f32_16x16x32_bf16(
                        af[i], bfr[j], acc[i][j], 0, 0, 0);
        }
        __syncthreads();   // compiler drains vmcnt(0) here: prefetch landed
    }

#pragma unroll
    for (int i = 0; i < FM; ++i) {
        const int mrow0 = m0 + wm + i * 16 + quad * 4;
#pragma unroll
        for (int j = 0; j < 4; ++j) {
            const int n  = n0 + wn + j * 16 + l16;
            const float bb = bias[n];
            if (MODE == 1) {
#pragma unroll
                for (int r = 0; r < 4; ++r)
                    outF[(size_t)(mrow0 + r) * 1024 + n] = acc[i][j][r] + bb;
            } else {
                const int h = n >> 6, hd = n & 63;
                if (proj == 2) {
                    const int b = mrow0 >> 11, s = mrow0 & 2047;
                    ushort4 pk;
                    pk.x = f2bf(acc[i][j][0] + bb);
                    pk.y = f2bf(acc[i][j][1] + bb);
                    pk.z = f2bf(acc[i][j][2] + bb);
                    pk.w = f2bf(acc[i][j][3] + bb);
                    *(ushort4*)(outV + ((size_t)((b * 16 + h) * 64 + hd)) * 2048 + s) = pk;
                } else {
                    unsigned short* dst = (proj == 0) ? outQ : outK;
                    const float scl = (proj == 0) ? (0.125f * LOG2E) : 1.0f;
#pragma unroll
                    for (int r = 0; r < 4; ++r) {
                        const int m = mrow0 + r;
                        const int b = m >> 11, s = m & 2047;
                        dst[((size_t)((b * 16 + h) * 2048 + s)) * 64 + hd] =
                            f2bf((acc[i][j][r] + bb) * scl);
                    }
                }
            }
        }
    }
}

// ---------------------------------------------------------------------------
// Flash attention, S^T form, x32 PV, s-split ACROSS WAVE-GROUPS, LDS combine.
// 512 blocks x 512 threads (8 waves). Waves 0-3 (grp 0): s in [0,1024);
// waves 4-7 (grp 1): s in [1024,2048). Each group: own 32KB K/V dbuf
// (64-s chunks), 4 waves x 32 q covering the same 128-q tile.
// 2 blocks/CU x 8 waves = 16 waves/CU (same TLP as r5's 4x4).
// XCD remap: bid%8 picks XCD; all 16 q-blocks of a head on one XCD -> K/V
// (512KB/head) L2-resident (proven: FETCH ~12MB).
// Epilogue: grp1 writes f32 partials (Osc[128][65] pad -> conflict-free) +
// lsums to LDS; barrier; grp0 adds, normalizes 1/(l0+l1), writes attnb.
// QK s->m remap: A-frag lane reads K row 32*st32 + 8*(l16>>2) + 4F + (l16&3),
// with Ks chunk swizzle g(s)=(s&3)|(((s>>3)&1)<<2) keeping reads conflict-free.
// C-frag(quad,reg r) holds s = 32*st32 + 8*quad + 4F + r -> packs directly
// into the 16x16x32 PV B-operand. Fixed-max softmax: p = exp2(acc), acc init
// = -10*log2e, log2e baked into Q. Thin pack: plain __bf16 casts.
// ---------------------------------------------------------------------------
__global__ __launch_bounds__(512) void attn_kernel(
    const unsigned short* __restrict__ Qb,   // [32][2048][64]
    const unsigned short* __restrict__ Kb,   // [32][2048][64]
    const unsigned short* __restrict__ Vtb,  // [32][64][2048]
    unsigned short* __restrict__ attnb)      // [4096][1024] bf16, normalized
{
    __shared__ __attribute__((aligned(16))) char SMEM[65536];   // 64 KB

    const int tid  = threadIdx.x;
    const int lane = tid & 63;
    const int wid  = tid >> 6;        // 0..7
    const int grp  = wid >> 2;        // s-half group
    const int qwid = wid & 3;         // wave within group
    const int gtid = tid & 255;       // thread id within group
    const int quad = lane >> 4;
    const int l16  = lane & 15;
    const int l7   = l16 & 7;

    // XCD-clustering bijective remap over 512 blocks:
    // bid -> (xcd c8, t); head = c8 + 8*(t>>4); qtile = t&15
    const int bid  = blockIdx.x + (blockIdx.y << 4);   // gridDim = (16, 32)
    const int c8   = bid & 7;
    const int t    = bid >> 3;          // 0..63
    const int hb   = c8 + ((t >> 4) << 3);
    const int qt16 = t & 15;
    const int q0   = qt16 * 128 + qwid * 32;
    const int bq   = hb >> 4, hh = hb & 15;

    const unsigned short* Qh  = Qb  + (size_t)hb * 2048 * 64;
    const unsigned short* Kh  = Kb  + (size_t)hb * 2048 * 64;
    const unsigned short* Vth = Vtb + (size_t)hb * 64 * 2048;

    // Q B-frags: B[k=d][n=q], lane n=l16, k=quad*8+j; kh = d-half
    bf16x8 qf[2][2];
#pragma unroll
    for (int qt = 0; qt < 2; ++qt) {
        const unsigned short* qp = Qh + (size_t)(q0 + qt * 16 + l16) * 64 + quad * 8;
        qf[qt][0] = *(const bf16x8*)(qp);
        qf[qt][1] = *(const bf16x8*)(qp + 32);
    }

    f32x4 o[4][2];   // O^T accumulators: [hd-tile][q-tile]
#pragma unroll
    for (int ht = 0; ht < 4; ++ht)
#pragma unroll
        for (int qt = 0; qt < 2; ++qt)
            o[ht][qt] = (f32x4){0.f, 0.f, 0.f, 0.f};
    float lsum[2] = {0.f, 0.f};

    char* base = SMEM + grp * 32768;
    char* KsB  = base;            // 2 x 64 x 64 bf16 = 16 KB
    char* VsB  = base + 16384;    // 2 x 64 x 64 bf16 = 16 KB

    auto stageKV = [&](int kc, int buf) {
        char* ldsK = KsB + buf * 8192 + qwid * 1024;
#pragma unroll
        for (int q = 0; q < 2; ++q) {
            int i   = q * 256 + gtid;
            int row = i >> 3;
            int g   = (row & 3) | (((row >> 3) & 1) << 2);
            int ch  = (i & 7) ^ g;
            glds16(Kh + (size_t)(kc + row) * 64 + ch * 8, ldsK + q * 4096);
        }
        char* ldsV = VsB + buf * 8192 + qwid * 1024;
#pragma unroll
        for (int q = 0; q < 2; ++q) {
            int i   = q * 256 + gtid;
            int row = i >> 3;
            int ch  = (i & 7) ^ (row & 7);
            glds16(Vth + (size_t)row * 2048 + kc + ch * 8, ldsV + q * 4096);
        }
    };

    // lane-constant pieces of the fragment addresses
    const int base_row = 8 * (l16 >> 2) + (l16 & 3);   // K s->m remap, F=0
    const int kp0 = ((quad) ^ l7) * 16;                // d-half 0 chunk
    const int kp1 = ((4 + quad) ^ l7) * 16;            // d-half 1 chunk
    const int vrow = l16 * 128;

    const int kc0 = grp * 1024;
    // prologue: stage first 64-s chunk into buf 0
    stageKV(kc0, 0);
    __syncthreads();

    for (int kc = kc0; kc < kc0 + 1024; kc += 64) {
        const int cur = (kc >> 6) & 1;
        if (kc + 64 < kc0 + 1024) stageKV(kc + 64, cur ^ 1);   // issue-early

        const char* KsC = KsB + cur * 8192;
        const char* VsC = VsB + cur * 8192;

#pragma unroll
        for (int st32 = 0; st32 < 2; ++st32) {   // 32 s per step
            const char* krb = KsC + (st32 * 32 + base_row) * 128;
            bf16x8 kf00 = *(const bf16x8*)(krb + kp0);
            bf16x8 kf01 = *(const bf16x8*)(krb + kp1);
            bf16x8 kf10 = *(const bf16x8*)(krb + 512 + kp0);   // F=1: +4 rows
            bf16x8 kf11 = *(const bf16x8*)(krb + 512 + kp1);

            const f32x4 mi = (f32x4){-FIXED_MAX_BITS, -FIXED_MAX_BITS,
                                     -FIXED_MAX_BITS, -FIXED_MAX_BITS};
            f32x4 s00 = mi, s01 = mi, s10 = mi, s11 = mi;  // [qt][F]
            s00 = __builtin_amdgcn_mfma_f32_16x16x32_bf16(kf00, qf[0][0], s00, 0, 0, 0);
            s00 = __builtin_amdgcn_mfma_f32_16x16x32_bf16(kf01, qf[0][1], s00, 0, 0, 0);
            s01 = __builtin_amdgcn_mfma_f32_16x16x32_bf16(kf10, qf[0][0], s01, 0, 0, 0);
            s01 = __builtin_amdgcn_mfma_f32_16x16x32_bf16(kf11, qf[0][1], s01, 0, 0, 0);
            s10 = __builtin_amdgcn_mfma_f32_16x16x32_bf16(kf00, qf[1][0], s10, 0, 0, 0);
            s10 = __builtin_amdgcn_mfma_f32_16x16x32_bf16(kf01, qf[1][1], s10, 0, 0, 0);
            s11 = __builtin_amdgcn_mfma_f32_16x16x32_bf16(kf10, qf[1][0], s11, 0, 0, 0);
            s11 = __builtin_amdgcn_mfma_f32_16x16x32_bf16(kf11, qf[1][1], s11, 0, 0, 0);

            bf16x8 p8[2];
#pragma unroll
            for (int qt = 0; qt < 2; ++qt) {
                const f32x4 sA = qt ? s10 : s00;
                const f32x4 sB = qt ? s11 : s01;
                float e0 = exp2_fast(sA[0]), e1 = exp2_fast(sA[1]);
                float e2 = exp2_fast(sA[2]), e3 = exp2_fast(sA[3]);
                float e4 = exp2_fast(sB[0]), e5 = exp2_fast(sB[1]);
                float e6 = exp2_fast(sB[2]), e7 = exp2_fast(sB[3]);
                lsum[qt] += ((e0 + e1) + (e2 + e3)) + ((e4 + e5) + (e6 + e7));
                // plain casts -> compiler emits packed v_cvt_pk_bf16_f32 (RNE)
                bf16x8 p;
                p[0] = (__bf16)e0; p[1] = (__bf16)e1;
                p[2] = (__bf16)e2; p[3] = (__bf16)e3;
                p[4] = (__bf16)e4; p[5] = (__bf16)e5;
                p[6] = (__bf16)e6; p[7] = (__bf16)e7;
                p8[qt] = p;
            }

            // V A-frags: one b128 per ht, chunk st32*4+quad (swizzled)
            const int voff = vrow + (((st32 * 4 + quad) ^ l7) * 16);
#pragma unroll
            for (int ht = 0; ht < 4; ++ht) {
                const bf16x8 vf = *(const bf16x8*)(VsC + voff + ht * 2048);
                o[ht][0] = __builtin_amdgcn_mfma_f32_16x16x32_bf16(vf, p8[0], o[ht][0], 0, 0, 0);
                o[ht][1] = __builtin_amdgcn_mfma_f32_16x16x32_bf16(vf, p8[1], o[ht][1], 0, 0, 0);
            }
        }
        __syncthreads();   // drains vmcnt(0): prefetch landed, buffers flip
    }
    // final loop barrier passed: no further K/V LDS access; SMEM reusable.

    // reduce lsum across quads (same l16 holds same q)
    float lt[2];
#pragma unroll
    for (int qt = 0; qt < 2; ++qt) {
        float s = lsum[qt];
        s += __shfl_xor(s, 16);
        s += __shfl_xor(s, 32);
        lt[qt] = s;
    }

    // ---- in-LDS f32 combine of the two s-half groups ----
    float* Osc = (float*)SMEM;                       // [128][65] padded, 33.3KB
    float* Lsc = (float*)(SMEM + 128 * 65 * 4);      // [128]

    if (grp == 1) {
#pragma unroll
        for (int qt = 0; qt < 2; ++qt) {
            const int ql = qwid * 32 + qt * 16 + l16;
#pragma unroll
            for (int ht = 0; ht < 4; ++ht) {
#pragma unroll
                for (int r = 0; r < 4; ++r)
                    Osc[ql * 65 + ht * 16 + quad * 4 + r] = o[ht][qt][r];
            }
            if (quad == 0) Lsc[ql] = lt[qt];
        }
    }
    __syncthreads();
    if (grp == 0) {
#pragma unroll
        for (int qt = 0; qt < 2; ++qt) {
            const int ql = qwid * 32 + qt * 16 + l16;
            const float rl = 1.0f / (lt[qt] + Lsc[ql]);
            const size_t row = (size_t)(bq * 2048 + q0 + qt * 16 + l16);
#pragma unroll
            for (int ht = 0; ht < 4; ++ht) {
                const float* op = &Osc[ql * 65 + ht * 16 + quad * 4];
                ushort4 pk;
                pk.x = f2bf((o[ht][qt][0] + op[0]) * rl);
                pk.y = f2bf((o[ht][qt][1] + op[1]) * rl);
                pk.z = f2bf((o[ht][qt][2] + op[2]) * rl);
                pk.w = f2bf((o[ht][qt][3] + op[3]) * rl);
                *(ushort4*)(attnb + row * 1024 + hh * 64 + ht * 16 + quad * 4) = pk;
            }
        }
    }
}

// ---------------------------------------------------------------------------
// launch
// ---------------------------------------------------------------------------
extern "C" void kernel_launch(void* const* d_in, const int* in_sizes, int n_in,
                              void* d_out, int out_size, void* d_ws, size_t ws_size,
                              hipStream_t stream) {
    (void)in_sizes; (void)n_in; (void)out_size; (void)ws_size;

    const float* x  = (const float*)d_in[0];
    const float* Wq = (const float*)d_in[1];
    const float* bq = (const float*)d_in[2];
    const float* Wk = (const float*)d_in[3];
    const float* bk = (const float*)d_in[4];
    const float* Wv = (const float*)d_in[5];
    const float* bv = (const float*)d_in[6];
    const float* Wo = (const float*)d_in[7];
    const float* bo = (const float*)d_in[8];

    char* ws = (char*)d_ws;
    const size_t MB = 1024 * 1024;
    unsigned short* xb    = (unsigned short*)(ws + 0);        //  8 MB [4096][1024]
    unsigned short* Wqb   = (unsigned short*)(ws + 8  * MB);  //  2 MB
    unsigned short* Wkb   = (unsigned short*)(ws + 10 * MB);
    unsigned short* Wvb   = (unsigned short*)(ws + 12 * MB);
    unsigned short* Wob   = (unsigned short*)(ws + 14 * MB);
    unsigned short* Qb    = (unsigned short*)(ws + 16 * MB);  //  8 MB [32][2048][64]
    unsigned short* Kb    = (unsigned short*)(ws + 24 * MB);  //  8 MB
    unsigned short* Vtb   = (unsigned short*)(ws + 32 * MB);  //  8 MB [32][64][2048]
    unsigned short* attnb = (unsigned short*)(ws + 40 * MB);  //  8 MB [4096][1024]

    cvt_all<<<dim3(1024), dim3(256), 0, stream>>>(
        x, Wq, Wk, Wv, Wo, xb, Wqb, Wkb, Wvb, Wob);

    gemm_bt<0><<<dim3(32, 24), dim3(256), 0, stream>>>(
        xb, Wqb, Wkb, Wvb, bq, bk, bv, Qb, Kb, Vtb, nullptr);

    attn_kernel<<<dim3(16, 32), dim3(512), 0, stream>>>(Qb, Kb, Vtb, attnb);

    gemm_bt<1><<<dim3(64, 8), dim3(256), 0, stream>>>(
        attnb, Wob, nullptr, nullptr, bo, nullptr, nullptr,
        nullptr, nullptr, nullptr, (float*)d_out);
}

// Round 9
// 181.268 us; speedup vs baseline: 1.4339x; 1.0069x over previous
//
#include <hip/hip_runtime.h>
#include <stdint.h>

// ---------------------------------------------------------------------------
// MultiHeadAttention  B=2 S=2048 D=1024 H=16 HD=64   (fp32 in/out, bf16 MFMA)
// convert->bf16, fused QKV GEMM, flash attention (S^T form, x32 PV, s-split
// across wave-groups with in-LDS f32 combine), output GEMM.
// Round change vs r8: gemm0 was latency-bound (MfmaUtil 22%, VALU 14%,
// occupancy 14%; 64KB LDS -> 2 blocks/CU; 768 blocks over 512 slots = 1.5
// dispatch rounds). Shrink gemm0 to BM=64 (template param): LDS 48KB ->
// 3 blocks/CU = 12 waves/CU, grid (64,24) = 1536 = exactly 2 rounds, no
// tail. XCD A-panel locality preserved (bid%8 = x%8). attn/gemm1/cvt
// unchanged from r8.
// ---------------------------------------------------------------------------

typedef __bf16 bf16x8 __attribute__((ext_vector_type(8)));
typedef float  f32x4  __attribute__((ext_vector_type(4)));

#define LOG2E 1.44269504088896f
#define FIXED_MAX_BITS 14.4269504088896f   /* 10 nats * log2(e) */

__device__ __forceinline__ unsigned short f2bf(float f) {
    union { float f; unsigned u; } v; v.f = f;
    unsigned r = v.u + 0x7FFFu + ((v.u >> 16) & 1u);   // round-to-nearest-even
    return (unsigned short)(r >> 16);
}

__device__ __forceinline__ float exp2_fast(float x) {
#if __has_builtin(__builtin_amdgcn_exp2f)
    return __builtin_amdgcn_exp2f(x);
#else
    return __expf(x * 0.69314718056f);
#endif
}

// async global->LDS, 16B per lane; lds dest = wave-uniform base + lane*16
__device__ __forceinline__ void glds16(const void* g, void* l) {
    __builtin_amdgcn_global_load_lds(
        (__attribute__((address_space(1))) void*)(g),
        (__attribute__((address_space(3))) void*)(l),
        16, 0, 0);
}

// ---------------------------------------------------------------------------
// fp32 -> bf16 convert: x (1M float4) + 4 weights (256K float4 each), 1 launch
// ---------------------------------------------------------------------------
__global__ __launch_bounds__(256) void cvt_all(
    const float* __restrict__ x,  const float* __restrict__ Wq,
    const float* __restrict__ Wk, const float* __restrict__ Wv,
    const float* __restrict__ Wo,
    unsigned short* __restrict__ xb,  unsigned short* __restrict__ Wqb,
    unsigned short* __restrict__ Wkb, unsigned short* __restrict__ Wvb,
    unsigned short* __restrict__ Wob)
{
    const int stride = gridDim.x * blockDim.x;
    for (int i = blockIdx.x * blockDim.x + threadIdx.x; i < 2097152; i += stride) {
        const float* src; unsigned short* dst; int j;
        if (i < 1048576) { src = x; dst = xb; j = i; }
        else {
            int t = (i - 1048576) >> 18; j = (i - 1048576) & 262143;
            src = (t == 0) ? Wq : (t == 1) ? Wk : (t == 2) ? Wv : Wo;
            dst = (t == 0) ? Wqb : (t == 1) ? Wkb : (t == 2) ? Wvb : Wob;
        }
        float4 v = ((const float4*)src)[j];
        ushort4 o;
        o.x = f2bf(v.x); o.y = f2bf(v.y); o.z = f2bf(v.z); o.w = f2bf(v.w);
        ((ushort4*)dst)[j] = o;
    }
}

// ---------------------------------------------------------------------------
// GEMM  C[m][n] = sum_k A[m][k] * W[n][k]  (+bias), 2-phase LDS double-buffer
// MODE 0: 3 projections (Q/K/V layouts); MODE 1: plain f32 out (final proj).
// BM parameterized: 64 -> 48KB LDS, 3 blocks/CU (occupancy over tile size).
// ---------------------------------------------------------------------------
template <int MODE, int BM>
__global__ __launch_bounds__(256) void gemm_bt(
    const unsigned short* __restrict__ A,
    const unsigned short* __restrict__ W0,
    const unsigned short* __restrict__ W1,
    const unsigned short* __restrict__ W2,
    const float* __restrict__ b0,
    const float* __restrict__ b1,
    const float* __restrict__ b2,
    unsigned short* __restrict__ outQ,
    unsigned short* __restrict__ outK,
    unsigned short* __restrict__ outV,
    float* __restrict__ outF)
{
    constexpr int FM = BM / 32;
    constexpr int RA = BM / 32;

    __shared__ __attribute__((aligned(16))) unsigned short As[2 * BM * 64];
    __shared__ __attribute__((aligned(16))) unsigned short Bs[2 * 128 * 64];

    const int tid  = threadIdx.x;
    const int lane = tid & 63;
    const int wid  = tid >> 6;
    const int quad = lane >> 4;
    const int l16  = lane & 15;

    const int m0 = blockIdx.x * BM;

    const unsigned short* W;
    const float* bias;
    int proj, n0;
    if (MODE == 0) {
        proj = blockIdx.y >> 3;
        n0   = (blockIdx.y & 7) * 128;
        W    = (proj == 0) ? W0 : (proj == 1) ? W1 : W2;
        bias = (proj == 0) ? b0 : (proj == 1) ? b1 : b2;
    } else {
        proj = 0;
        n0   = blockIdx.y * 128;
        W    = W0;
        bias = b0;
    }

    const int wm = (wid >> 1) * (BM / 2);
    const int wn = (wid & 1) * 64;

    f32x4 acc[FM][4];
#pragma unroll
    for (int i = 0; i < FM; ++i)
#pragma unroll
        for (int j = 0; j < 4; ++j)
            acc[i][j] = (f32x4){0.f, 0.f, 0.f, 0.f};

    char* AsB = (char*)As;
    char* BsB = (char*)Bs;

    auto stageAB = [&](int k0, int buf) {
        char* ldsA = AsB + buf * (BM * 128) + wid * 1024;
        char* ldsB = BsB + buf * 16384 + wid * 1024;
#pragma unroll
        for (int q = 0; q < RA; ++q) {
            int i   = q * 256 + tid;
            int row = i >> 3;
            int sc  = (i & 7) ^ (row & 7);
            glds16(A + (size_t)(m0 + row) * 1024 + k0 + sc * 8, ldsA + q * 4096);
        }
#pragma unroll
        for (int q = 0; q < 4; ++q) {
            int i   = q * 256 + tid;
            int row = i >> 3;
            int sc  = (i & 7) ^ (row & 7);
            glds16(W + (size_t)(n0 + row) * 1024 + k0 + sc * 8, ldsB + q * 4096);
        }
    };

    // prologue: stage first K-tile into buf 0
    stageAB(0, 0);
    __syncthreads();

    for (int k0 = 0; k0 < 1024; k0 += 64) {
        const int cur = (k0 >> 6) & 1;
        if (k0 + 64 < 1024) stageAB(k0 + 64, cur ^ 1);   // issue-early prefetch

        const char* AsC = AsB + cur * (BM * 128);
        const char* BsC = BsB + cur * 16384;

#pragma unroll
        for (int kh = 0; kh < 2; ++kh) {
            bf16x8 af[FM], bfr[4];
#pragma unroll
            for (int t = 0; t < FM; ++t) {
                int r = wm + t * 16 + l16;
                int c = (kh * 4 + quad) ^ (r & 7);
                af[t] = *(const bf16x8*)(AsC + r * 128 + c * 16);
            }
#pragma unroll
            for (int t = 0; t < 4; ++t) {
                int r = wn + t * 16 + l16;
                int c = (kh * 4 + quad) ^ (r & 7);
                bfr[t] = *(const bf16x8*)(BsC + r * 128 + c * 16);
            }
#pragma unroll
            for (int i = 0; i < FM; ++i)
#pragma unroll
                for (int j = 0; j < 4; ++j)
                    acc[i][j] = __builtin_amdgcn_mfma_f32_16x16x32_bf16(
                        af[i], bfr[j], acc[i][j], 0, 0, 0);
        }
        __syncthreads();   // compiler drains vmcnt(0) here: prefetch landed
    }

#pragma unroll
    for (int i = 0; i < FM; ++i) {
        const int mrow0 = m0 + wm + i * 16 + quad * 4;
#pragma unroll
        for (int j = 0; j < 4; ++j) {
            const int n  = n0 + wn + j * 16 + l16;
            const float bb = bias[n];
            if (MODE == 1) {
#pragma unroll
                for (int r = 0; r < 4; ++r)
                    outF[(size_t)(mrow0 + r) * 1024 + n] = acc[i][j][r] + bb;
            } else {
                const int h = n >> 6, hd = n & 63;
                if (proj == 2) {
                    const int b = mrow0 >> 11, s = mrow0 & 2047;
                    ushort4 pk;
                    pk.x = f2bf(acc[i][j][0] + bb);
                    pk.y = f2bf(acc[i][j][1] + bb);
                    pk.z = f2bf(acc[i][j][2] + bb);
                    pk.w = f2bf(acc[i][j][3] + bb);
                    *(ushort4*)(outV + ((size_t)((b * 16 + h) * 64 + hd)) * 2048 + s) = pk;
                } else {
                    unsigned short* dst = (proj == 0) ? outQ : outK;
                    const float scl = (proj == 0) ? (0.125f * LOG2E) : 1.0f;
#pragma unroll
                    for (int r = 0; r < 4; ++r) {
                        const int m = mrow0 + r;
                        const int b = m >> 11, s = m & 2047;
                        dst[((size_t)((b * 16 + h) * 2048 + s)) * 64 + hd] =
                            f2bf((acc[i][j][r] + bb) * scl);
                    }
                }
            }
        }
    }
}

// ---------------------------------------------------------------------------
// Flash attention, S^T form, x32 PV, s-split ACROSS WAVE-GROUPS, LDS combine.
// 512 blocks x 512 threads (8 waves). Waves 0-3 (grp 0): s in [0,1024);
// waves 4-7 (grp 1): s in [1024,2048). Each group: own 32KB K/V dbuf
// (64-s chunks), 4 waves x 32 q covering the same 128-q tile.
// 2 blocks/CU x 8 waves = 16 waves/CU (same TLP as r5's 4x4).
// XCD remap: bid%8 picks XCD; all 16 q-blocks of a head on one XCD -> K/V
// (512KB/head) L2-resident (proven: FETCH ~12MB).
// Epilogue: grp1 writes f32 partials (Osc[128][65] pad -> conflict-free) +
// lsums to LDS; barrier; grp0 adds, normalizes 1/(l0+l1), writes attnb.
// QK s->m remap: A-frag lane reads K row 32*st32 + 8*(l16>>2) + 4F + (l16&3),
// with Ks chunk swizzle g(s)=(s&3)|(((s>>3)&1)<<2) keeping reads conflict-free.
// C-frag(quad,reg r) holds s = 32*st32 + 8*quad + 4F + r -> packs directly
// into the 16x16x32 PV B-operand. Fixed-max softmax: p = exp2(acc), acc init
// = -10*log2e, log2e baked into Q. Thin pack: plain __bf16 casts.
// ---------------------------------------------------------------------------
__global__ __launch_bounds__(512) void attn_kernel(
    const unsigned short* __restrict__ Qb,   // [32][2048][64]
    const unsigned short* __restrict__ Kb,   // [32][2048][64]
    const unsigned short* __restrict__ Vtb,  // [32][64][2048]
    unsigned short* __restrict__ attnb)      // [4096][1024] bf16, normalized
{
    __shared__ __attribute__((aligned(16))) char SMEM[65536];   // 64 KB

    const int tid  = threadIdx.x;
    const int lane = tid & 63;
    const int wid  = tid >> 6;        // 0..7
    const int grp  = wid >> 2;        // s-half group
    const int qwid = wid & 3;         // wave within group
    const int gtid = tid & 255;       // thread id within group
    const int quad = lane >> 4;
    const int l16  = lane & 15;
    const int l7   = l16 & 7;

    // XCD-clustering bijective remap over 512 blocks:
    // bid -> (xcd c8, t); head = c8 + 8*(t>>4); qtile = t&15
    const int bid  = blockIdx.x + (blockIdx.y << 4);   // gridDim = (16, 32)
    const int c8   = bid & 7;
    const int t    = bid >> 3;          // 0..63
    const int hb   = c8 + ((t >> 4) << 3);
    const int qt16 = t & 15;
    const int q0   = qt16 * 128 + qwid * 32;
    const int bq   = hb >> 4, hh = hb & 15;

    const unsigned short* Qh  = Qb  + (size_t)hb * 2048 * 64;
    const unsigned short* Kh  = Kb  + (size_t)hb * 2048 * 64;
    const unsigned short* Vth = Vtb + (size_t)hb * 64 * 2048;

    // Q B-frags: B[k=d][n=q], lane n=l16, k=quad*8+j; kh = d-half
    bf16x8 qf[2][2];
#pragma unroll
    for (int qt = 0; qt < 2; ++qt) {
        const unsigned short* qp = Qh + (size_t)(q0 + qt * 16 + l16) * 64 + quad * 8;
        qf[qt][0] = *(const bf16x8*)(qp);
        qf[qt][1] = *(const bf16x8*)(qp + 32);
    }

    f32x4 o[4][2];   // O^T accumulators: [hd-tile][q-tile]
#pragma unroll
    for (int ht = 0; ht < 4; ++ht)
#pragma unroll
        for (int qt = 0; qt < 2; ++qt)
            o[ht][qt] = (f32x4){0.f, 0.f, 0.f, 0.f};
    float lsum[2] = {0.f, 0.f};

    char* base = SMEM + grp * 32768;
    char* KsB  = base;            // 2 x 64 x 64 bf16 = 16 KB
    char* VsB  = base + 16384;    // 2 x 64 x 64 bf16 = 16 KB

    auto stageKV = [&](int kc, int buf) {
        char* ldsK = KsB + buf * 8192 + qwid * 1024;
#pragma unroll
        for (int q = 0; q < 2; ++q) {
            int i   = q * 256 + gtid;
            int row = i >> 3;
            int g   = (row & 3) | (((row >> 3) & 1) << 2);
            int ch  = (i & 7) ^ g;
            glds16(Kh + (size_t)(kc + row) * 64 + ch * 8, ldsK + q * 4096);
        }
        char* ldsV = VsB + buf * 8192 + qwid * 1024;
#pragma unroll
        for (int q = 0; q < 2; ++q) {
            int i   = q * 256 + gtid;
            int row = i >> 3;
            int ch  = (i & 7) ^ (row & 7);
            glds16(Vth + (size_t)row * 2048 + kc + ch * 8, ldsV + q * 4096);
        }
    };

    // lane-constant pieces of the fragment addresses
    const int base_row = 8 * (l16 >> 2) + (l16 & 3);   // K s->m remap, F=0
    const int kp0 = ((quad) ^ l7) * 16;                // d-half 0 chunk
    const int kp1 = ((4 + quad) ^ l7) * 16;            // d-half 1 chunk
    const int vrow = l16 * 128;

    const int kc0 = grp * 1024;
    // prologue: stage first 64-s chunk into buf 0
    stageKV(kc0, 0);
    __syncthreads();

    for (int kc = kc0; kc < kc0 + 1024; kc += 64) {
        const int cur = (kc >> 6) & 1;
        if (kc + 64 < kc0 + 1024) stageKV(kc + 64, cur ^ 1);   // issue-early

        const char* KsC = KsB + cur * 8192;
        const char* VsC = VsB + cur * 8192;

#pragma unroll
        for (int st32 = 0; st32 < 2; ++st32) {   // 32 s per step
            const char* krb = KsC + (st32 * 32 + base_row) * 128;
            bf16x8 kf00 = *(const bf16x8*)(krb + kp0);
            bf16x8 kf01 = *(const bf16x8*)(krb + kp1);
            bf16x8 kf10 = *(const bf16x8*)(krb + 512 + kp0);   // F=1: +4 rows
            bf16x8 kf11 = *(const bf16x8*)(krb + 512 + kp1);

            const f32x4 mi = (f32x4){-FIXED_MAX_BITS, -FIXED_MAX_BITS,
                                     -FIXED_MAX_BITS, -FIXED_MAX_BITS};
            f32x4 s00 = mi, s01 = mi, s10 = mi, s11 = mi;  // [qt][F]
            s00 = __builtin_amdgcn_mfma_f32_16x16x32_bf16(kf00, qf[0][0], s00, 0, 0, 0);
            s00 = __builtin_amdgcn_mfma_f32_16x16x32_bf16(kf01, qf[0][1], s00, 0, 0, 0);
            s01 = __builtin_amdgcn_mfma_f32_16x16x32_bf16(kf10, qf[0][0], s01, 0, 0, 0);
            s01 = __builtin_amdgcn_mfma_f32_16x16x32_bf16(kf11, qf[0][1], s01, 0, 0, 0);
            s10 = __builtin_amdgcn_mfma_f32_16x16x32_bf16(kf00, qf[1][0], s10, 0, 0, 0);
            s10 = __builtin_amdgcn_mfma_f32_16x16x32_bf16(kf01, qf[1][1], s10, 0, 0, 0);
            s11 = __builtin_amdgcn_mfma_f32_16x16x32_bf16(kf10, qf[1][0], s11, 0, 0, 0);
            s11 = __builtin_amdgcn_mfma_f32_16x16x32_bf16(kf11, qf[1][1], s11, 0, 0, 0);

            bf16x8 p8[2];
#pragma unroll
            for (int qt = 0; qt < 2; ++qt) {
                const f32x4 sA = qt ? s10 : s00;
                const f32x4 sB = qt ? s11 : s01;
                float e0 = exp2_fast(sA[0]), e1 = exp2_fast(sA[1]);
                float e2 = exp2_fast(sA[2]), e3 = exp2_fast(sA[3]);
                float e4 = exp2_fast(sB[0]), e5 = exp2_fast(sB[1]);
                float e6 = exp2_fast(sB[2]), e7 = exp2_fast(sB[3]);
                lsum[qt] += ((e0 + e1) + (e2 + e3)) + ((e4 + e5) + (e6 + e7));
                // plain casts -> compiler emits packed v_cvt_pk_bf16_f32 (RNE)
                bf16x8 p;
                p[0] = (__bf16)e0; p[1] = (__bf16)e1;
                p[2] = (__bf16)e2; p[3] = (__bf16)e3;
                p[4] = (__bf16)e4; p[5] = (__bf16)e5;
                p[6] = (__bf16)e6; p[7] = (__bf16)e7;
                p8[qt] = p;
            }

            // V A-frags: one b128 per ht, chunk st32*4+quad (swizzled)
            const int voff = vrow + (((st32 * 4 + quad) ^ l7) * 16);
#pragma unroll
            for (int ht = 0; ht < 4; ++ht) {
                const bf16x8 vf = *(const bf16x8*)(VsC + voff + ht * 2048);
                o[ht][0] = __builtin_amdgcn_mfma_f32_16x16x32_bf16(vf, p8[0], o[ht][0], 0, 0, 0);
                o[ht][1] = __builtin_amdgcn_mfma_f32_16x16x32_bf16(vf, p8[1], o[ht][1], 0, 0, 0);
            }
        }
        __syncthreads();   // drains vmcnt(0): prefetch landed, buffers flip
    }
    // final loop barrier passed: no further K/V LDS access; SMEM reusable.

    // reduce lsum across quads (same l16 holds same q)
    float lt[2];
#pragma unroll
    for (int qt = 0; qt < 2; ++qt) {
        float s = lsum[qt];
        s += __shfl_xor(s, 16);
        s += __shfl_xor(s, 32);
        lt[qt] = s;
    }

    // ---- in-LDS f32 combine of the two s-half groups ----
    float* Osc = (float*)SMEM;                       // [128][65] padded, 33.3KB
    float* Lsc = (float*)(SMEM + 128 * 65 * 4);      // [128]

    if (grp == 1) {
#pragma unroll
        for (int qt = 0; qt < 2; ++qt) {
            const int ql = qwid * 32 + qt * 16 + l16;
#pragma unroll
            for (int ht = 0; ht < 4; ++ht) {
#pragma unroll
                for (int r = 0; r < 4; ++r)
                    Osc[ql * 65 + ht * 16 + quad * 4 + r] = o[ht][qt][r];
            }
            if (quad == 0) Lsc[ql] = lt[qt];
        }
    }
    __syncthreads();
    if (grp == 0) {
#pragma unroll
        for (int qt = 0; qt < 2; ++qt) {
            const int ql = qwid * 32 + qt * 16 + l16;
            const float rl = 1.0f / (lt[qt] + Lsc[ql]);
            const size_t row = (size_t)(bq * 2048 + q0 + qt * 16 + l16);
#pragma unroll
            for (int ht = 0; ht < 4; ++ht) {
                const float* op = &Osc[ql * 65 + ht * 16 + quad * 4];
                ushort4 pk;
                pk.x = f2bf((o[ht][qt][0] + op[0]) * rl);
                pk.y = f2bf((o[ht][qt][1] + op[1]) * rl);
                pk.z = f2bf((o[ht][qt][2] + op[2]) * rl);
                pk.w = f2bf((o[ht][qt][3] + op[3]) * rl);
                *(ushort4*)(attnb + row * 1024 + hh * 64 + ht * 16 + quad * 4) = pk;
            }
        }
    }
}

// ---------------------------------------------------------------------------
// launch
// ---------------------------------------------------------------------------
extern "C" void kernel_launch(void* const* d_in, const int* in_sizes, int n_in,
                              void* d_out, int out_size, void* d_ws, size_t ws_size,
                              hipStream_t stream) {
    (void)in_sizes; (void)n_in; (void)out_size; (void)ws_size;

    const float* x  = (const float*)d_in[0];
    const float* Wq = (const float*)d_in[1];
    const float* bq = (const float*)d_in[2];
    const float* Wk = (const float*)d_in[3];
    const float* bk = (const float*)d_in[4];
    const float* Wv = (const float*)d_in[5];
    const float* bv = (const float*)d_in[6];
    const float* Wo = (const float*)d_in[7];
    const float* bo = (const float*)d_in[8];

    char* ws = (char*)d_ws;
    const size_t MB = 1024 * 1024;
    unsigned short* xb    = (unsigned short*)(ws + 0);        //  8 MB [4096][1024]
    unsigned short* Wqb   = (unsigned short*)(ws + 8  * MB);  //  2 MB
    unsigned short* Wkb   = (unsigned short*)(ws + 10 * MB);
    unsigned short* Wvb   = (unsigned short*)(ws + 12 * MB);
    unsigned short* Wob   = (unsigned short*)(ws + 14 * MB);
    unsigned short* Qb    = (unsigned short*)(ws + 16 * MB);  //  8 MB [32][2048][64]
    unsigned short* Kb    = (unsigned short*)(ws + 24 * MB);  //  8 MB
    unsigned short* Vtb   = (unsigned short*)(ws + 32 * MB);  //  8 MB [32][64][2048]
    unsigned short* attnb = (unsigned short*)(ws + 40 * MB);  //  8 MB [4096][1024]

    cvt_all<<<dim3(1024), dim3(256), 0, stream>>>(
        x, Wq, Wk, Wv, Wo, xb, Wqb, Wkb, Wvb, Wob);

    gemm_bt<0, 64><<<dim3(64, 24), dim3(256), 0, stream>>>(
        xb, Wqb, Wkb, Wvb, bq, bk, bv, Qb, Kb, Vtb, nullptr);

    attn_kernel<<<dim3(16, 32), dim3(512), 0, stream>>>(Qb, Kb, Vtb, attnb);

    gemm_bt<1, 64><<<dim3(64, 8), dim3(256), 0, stream>>>(
        attnb, Wob, nullptr, nullptr, bo, nullptr, nullptr,
        nullptr, nullptr, nullptr, (float*)d_out);
}